// Round 16
// baseline (305.310 us; speedup 1.0000x reference)
//
#include <hip/hip_runtime.h>

typedef unsigned short u16;
typedef __attribute__((ext_vector_type(8))) short s16x8;
typedef __attribute__((ext_vector_type(4))) float f32x4;

#define MFMA16(a,b,c) __builtin_amdgcn_mfma_f32_16x16x32_bf16((a),(b),(c),0,0,0)
#define LSEQ 2048
#define QSCALE 0.18033688011112042f  /* 0.125 * log2(e) */

__device__ __forceinline__ u16 f2b(float f) {
  union { float f; unsigned u; } v; v.f = f;
  unsigned r = v.u + 0x7FFFu + ((v.u >> 16) & 1u);
  return (u16)(r >> 16);
}
__device__ __forceinline__ void g2l16(const void* g, void* l) {
  __builtin_amdgcn_global_load_lds(
      (const __attribute__((address_space(1))) unsigned int*)g,
      (__attribute__((address_space(3))) unsigned int*)l, 16, 0, 0);
}

// ------------- fused prep: cvt(x), cvt(E), bias concat, 6 weight transposes -------------
__global__ __launch_bounds__(256) void k_prep_all(
    const float* __restrict__ x, const float* __restrict__ E,
    const float* __restrict__ bq, const float* __restrict__ bk, const float* __restrict__ bv,
    const float* __restrict__ Wq, const float* __restrict__ Wk, const float* __restrict__ Wv,
    const float* __restrict__ Wo, const float* __restrict__ W1, const float* __restrict__ W2,
    u16* __restrict__ xb, u16* __restrict__ Ebf, float* __restrict__ bcat,
    u16* __restrict__ Wqt, u16* __restrict__ Wot, u16* __restrict__ W1t, u16* __restrict__ W2t) {
  __shared__ float T[64][65];
  const int b = blockIdx.x, tid = threadIdx.x;

  if (b < 1056) {
    const float* src = (b < 1024) ? x : E;
    u16* dst = (b < 1024) ? xb : Ebf;
    const int base = (b < 1024) ? b * 4096 : (b - 1024) * 4096;
#pragma unroll
    for (int p = 0; p < 4; p++) {
      int i = base + p * 1024 + tid * 4;
      float4 v = *(const float4*)(src + i);
      ushort4 o;
      o.x = f2b(v.x); o.y = f2b(v.y); o.z = f2b(v.z); o.w = f2b(v.w);
      *(ushort4*)(dst + i) = o;
    }
    return;
  }
  if (b == 1056) {
    for (int i = tid; i < 3072; i += 256)
      bcat[i] = (i < 1024) ? bq[i] : (i < 2048) ? bk[i - 1024] : bv[i - 2048];
    return;
  }

  const int idx = b - 1057;
  const float* W; u16* Wt; int K, N, bx, by;
  if (idx < 1024) {
    const int m = idx >> 8, ti = idx & 255;
    const float* ws4[4] = {Wq, Wk, Wv, Wo};
    W = ws4[m];
    Wt = (m < 3) ? (Wqt + (size_t)m * 1048576) : Wot;
    K = 1024; N = 1024; bx = ti & 15; by = ti >> 4;
  } else if (idx < 2048) {
    const int ti = idx - 1024;
    W = W1; Wt = W1t; K = 1024; N = 4096; bx = ti & 63; by = ti >> 6;
  } else {
    const int ti = idx - 2048;
    W = W2; Wt = W2t; K = 4096; N = 1024; bx = ti & 15; by = ti >> 4;
  }
  const int k0 = by * 64, n0 = bx * 64;
  const int r = tid >> 4, c4 = (tid & 15) * 4;
#pragma unroll
  for (int i = 0; i < 4; i++) {
    float4 v = *(const float4*)(W + (size_t)(k0 + r + i * 16) * N + n0 + c4);
    T[r + i * 16][c4 + 0] = v.x; T[r + i * 16][c4 + 1] = v.y;
    T[r + i * 16][c4 + 2] = v.z; T[r + i * 16][c4 + 3] = v.w;
  }
  __syncthreads();
#pragma unroll
  for (int i = 0; i < 4; i++) {
    int nl = r + i * 16;
    ushort4 o;
    o.x = f2b(T[c4 + 0][nl]); o.y = f2b(T[c4 + 1][nl]);
    o.z = f2b(T[c4 + 2][nl]); o.w = f2b(T[c4 + 3][nl]);
    *(ushort4*)(Wt + (size_t)(n0 + nl) * K + k0 + c4) = o;
  }
}

// ------------- bf16 MFMA GEMM, gload_lds dbuf, swizzled LDS, BK=32/64 -------------
// BM=128: 4 waves.  BM=256 (BN=128): 8 waves, 64x64/wave.
// Bijective XCD-chunked block swizzle (grid % 8 == 0 for all call sites).
// FLAGS: 1=RELU, 2=BF16OUT, 4=QKV, 8=RESID_F32, 16=RESID_BF16
template <int BM, int BN, int FLAGS, int BK>
__global__ __launch_bounds__(BM == 256 ? 512 : 256, BM == 256 ? 4 : 2)
void k_gemm(const u16* __restrict__ A, const u16* __restrict__ Bt,
            const float* __restrict__ bias, const void* __restrict__ resid,
            void* __restrict__ Cout, int M, int N, int K) {
  constexpr int MI = (BN == 128) ? 4 : 2;
  constexpr int KH = BK / 32;
  __shared__ __align__(16) u16 As[2][KH][BM * 32];
  __shared__ __align__(16) u16 Bs[2][KH][BN * 32];
  const int tid = threadIdx.x;
  const int lane = tid & 63, wave = tid >> 6;
  const int lo = lane & 15, hi = lane >> 4;
  const int WROW = (BN == 128) ? (wave >> 1) * 64 : wave * 32;
  const int WCOL = (BN == 128) ? (wave & 1) * 64 : 0;

  // XCD-chunked bijective remap: XCD c gets logical chunk [c*nwg/8, (c+1)*nwg/8)
  const int nwgx = gridDim.x;
  const int nwg = nwgx * gridDim.y;
  int lid = blockIdx.y * nwgx + blockIdx.x;
  lid = (lid & 7) * (nwg >> 3) + (lid >> 3);
  const int m0 = (lid / nwgx) * BM, n0 = (lid % nwgx) * BN;

  const int colg = ((lane & 3) * 16) ^ (((lane >> 3) & 3) << 4);
  const int arow = wave * 32 + (lane >> 2);
  const int swzr = ((lane >> 1) & 3) << 4;

  f32x4 acc[MI][4];
#pragma unroll
  for (int mi = 0; mi < MI; mi++)
#pragma unroll
    for (int ni = 0; ni < 4; ni++) acc[mi][ni] = (f32x4){0.f, 0.f, 0.f, 0.f};

  const char* Ab = (const char*)A;
  const char* Bb = (const char*)Bt;
  const int nt = K / BK;

  auto stage = [&](int buf, int t) {
#pragma unroll
    for (int h = 0; h < KH; h++) {
      const int k0 = t * BK + h * 32;
      char* ad = (char*)&As[buf][h][0] + wave * 2048;
      const char* as = Ab + ((size_t)(m0 + arow) * K + k0) * 2 + colg;
      g2l16(as, ad);
      g2l16(as + (size_t)16 * K * 2, ad + 1024);
      if (BM == 256) {
        char* bd = (char*)&Bs[buf][h][0] + wave * 1024;
        const char* bs = Bb + ((size_t)(n0 + wave * 16 + (lane >> 2)) * K + k0) * 2 + colg;
        g2l16(bs, bd);
      } else if (BN == 128) {
        char* bd = (char*)&Bs[buf][h][0] + wave * 2048;
        const char* bs = Bb + ((size_t)(n0 + arow) * K + k0) * 2 + colg;
        g2l16(bs, bd);
        g2l16(bs + (size_t)16 * K * 2, bd + 1024);
      } else {
        char* bd = (char*)&Bs[buf][h][0] + wave * 1024;
        const int brow = wave * 16 + (lane >> 2);
        const char* bs = Bb + ((size_t)(n0 + brow) * K + k0) * 2 + colg;
        g2l16(bs, bd);
      }
    }
  };

  stage(0, 0);
  int buf = 0;
  for (int t = 0; t < nt; t++) {
    __syncthreads();
    if (t + 1 < nt) stage(buf ^ 1, t + 1);
#pragma unroll
    for (int h = 0; h < KH; h++) {
      const char* ab = (const char*)&As[buf][h][0];
      const char* bb2 = (const char*)&Bs[buf][h][0];
      s16x8 af[MI], bfr[4];
#pragma unroll
      for (int mi = 0; mi < MI; mi++) {
        int row = WROW + mi * 16 + lo;
        af[mi] = *(const s16x8*)(ab + row * 64 + ((hi * 16) ^ swzr));
      }
#pragma unroll
      for (int ni = 0; ni < 4; ni++) {
        int row = WCOL + ni * 16 + lo;
        bfr[ni] = *(const s16x8*)(bb2 + row * 64 + ((hi * 16) ^ swzr));
      }
#pragma unroll
      for (int mi = 0; mi < MI; mi++)
#pragma unroll
        for (int ni = 0; ni < 4; ni++)
          acc[mi][ni] = MFMA16(af[mi], bfr[ni], acc[mi][ni]);
    }
    buf ^= 1;
  }

#pragma unroll
  for (int mi = 0; mi < MI; mi++)
#pragma unroll
    for (int ni = 0; ni < 4; ni++) {
      const int mb = m0 + WROW + mi * 16 + hi * 4;
      const int n = n0 + WCOL + ni * 16 + lo;
      float v4[4];
#pragma unroll
      for (int reg = 0; reg < 4; reg++) {
        float v = acc[mi][ni][reg] + bias[n];
        if (FLAGS & 8) v += ((const float*)resid)[(size_t)(mb + reg) * N + n];
        if (FLAGS & 16) {
          union { unsigned u; float f; } q;
          q.u = ((unsigned)((const u16*)resid)[(size_t)(mb + reg) * N + n]) << 16;
          v += q.f;
        }
        if (FLAGS & 1) v = fmaxf(v, 0.f);
        v4[reg] = v;
      }
      if (FLAGS & 4) {
        const int seg = n >> 10, nn = n & 1023;
        const int hh = nn >> 6, dd = nn & 63;
        const int bb = mb >> 11, ll = mb & 2047;
        u16* dst = (u16*)Cout + (size_t)seg * 4194304;
        if (seg == 0) {
#pragma unroll
          for (int reg = 0; reg < 4; reg++)
            dst[((size_t)(bb * 16 + hh) * LSEQ + ll + reg) * 64 + dd] = f2b(v4[reg] * QSCALE);
        } else if (seg == 1) {
#pragma unroll
          for (int reg = 0; reg < 4; reg++)
            dst[((size_t)(bb * 16 + hh) * LSEQ + ll + reg) * 64 + dd] = f2b(v4[reg]);
        } else {
          // V^T, quad-permuted within each 32-seq group so k_attn reads b128 frags:
          // j-quad lq -> position quad (lq<4 ? 2lq : 2(lq-4)+1)
          const int lq = (ll >> 2) & 7;
          const int pq = (lq < 4) ? (lq * 2) : ((lq - 4) * 2 + 1);
          const int llp = (ll & ~31) | (pq << 2);
          ushort4 o;
          o.x = f2b(v4[0]); o.y = f2b(v4[1]); o.z = f2b(v4[2]); o.w = f2b(v4[3]);
          *(ushort4*)&((u16*)dst)[((size_t)(bb * 16 + hh) * 64 + dd) * LSEQ + llp] = o;
        }
      } else if (FLAGS & 2) {
        u16* dst = (u16*)Cout;
#pragma unroll
        for (int reg = 0; reg < 4; reg++) dst[(size_t)(mb + reg) * N + n] = f2b(v4[reg]);
      } else {
        float* dst = (float*)Cout;
#pragma unroll
        for (int reg = 0; reg < 4; reg++) dst[(size_t)(mb + reg) * N + n] = v4[reg];
      }
    }
}

// ------------- fused rel-pos flash attention: transposed dataflow, 8 waves/block -------------
// V stored quad-permuted -> V frags are 2x ds_read_b128 with K-style addressing.
// First two E-load pairs issued before the QK MFMA cluster (latency hidden under it).
__global__ __launch_bounds__(512, 4) void k_attn(const u16* __restrict__ Qh, const u16* __restrict__ Kh,
                                                 const u16* __restrict__ Vt, const u16* __restrict__ Eb,
                                                 u16* __restrict__ Ob) {
  __shared__ __align__(16) u16 Ksh[2][64 * 64];
  __shared__ __align__(16) u16 Vts[2][64 * 64];
  __shared__ __align__(16) float Gsh[8][16 * 84];

  const int tid = threadIdx.x;
  const int lane = tid & 63, wave = tid >> 6;
  const int lo = lane & 15, hi = lane >> 4;

  const int hb = blockIdx.x;
  const int x = hb & 7;
  const int kk = hb >> 3;
  const int bh = x * 4 + (kk >> 4);
  const int ti = (kk & 32) ? (15 - (kk & 15)) : (kk & 15);
  const int l0 = ti * 128;
  const int bb = bh >> 4, hh = bh & 15;
  const int lw = l0 + wave * 16;

  const u16* Qb = Qh + (size_t)bh * LSEQ * 64;
  const char* Kb = (const char*)(Kh + (size_t)bh * LSEQ * 64);
  const char* Vb = (const char*)(Vt + (size_t)bh * 64 * LSEQ);

  const int colsw = ((lane & 7) * 16) ^ (((lane >> 3) & 7) << 4);
  const int swzv = (lo & 7) << 4;
  const int c0 = (hi * 16) ^ swzv;

  auto stageKV = [&](int buf_, int j0_) {
    char* kd = (char*)&Ksh[buf_][0] + wave * 1024;
    const char* ks = Kb + (size_t)(j0_ + wave * 8 + (lane >> 3)) * 128 + colsw;
    g2l16(ks, kd);
    char* vd = (char*)&Vts[buf_][0] + wave * 1024;
    const char* vs = Vb + (size_t)(wave * 8 + (lane >> 3)) * (LSEQ * 2) + (size_t)j0_ * 2 + colsw;
    g2l16(vs, vd);
  };

  s16x8 aq[2];
  aq[0] = *(const s16x8*)(Qb + (size_t)(lw + lo) * 64 + hi * 8);
  aq[1] = *(const s16x8*)(Qb + (size_t)(lw + lo) * 64 + 32 + hi * 8);

  const s16x8 ones8 = {16256, 16256, 16256, 16256, 16256, 16256, 16256, 16256};  // bf16 1.0

  float m_run = -1e30f, l_run = 0.f;
  f32x4 oacc[4];
#pragma unroll
  for (int f = 0; f < 4; f++) oacc[f] = (f32x4){0.f, 0.f, 0.f, 0.f};

  float* gw = &Gsh[wave][0];

  stageKV(0, 0);
  int buf = 0;

  for (int t = 0; t < 32; t++) {
    const int j0 = t * 64;
    const bool has_rel = (j0 <= lw);
    __syncthreads();
    if (t < 31) stageKV(buf ^ 1, j0 + 64);

    // E pairs 0 and 1 issued EARLY (hidden under the QK cluster); slots rotate a/b.
    s16x8 ea0, ea1, eb0, eb1;
    const u16* ep0 = Eb;
    if (has_rel) {
      const int waveBase = 2032 - lw + j0;
      ep0 = Eb + (size_t)(waveBase + lo) * 64 + hi * 8;
      ea0 = *(const s16x8*)(ep0);
      ea1 = *(const s16x8*)(ep0 + 32);
      eb0 = *(const s16x8*)(ep0 + 16 * 64);
      eb1 = *(const s16x8*)(ep0 + 16 * 64 + 32);
    }

    // S^T = mfma(K, Q)
    f32x4 s4[4];
#pragma unroll
    for (int c = 0; c < 4; c++) {
      const char* krow = (const char*)&Ksh[buf][0] + (c * 16 + lo) * 128;
      s16x8 a0 = *(const s16x8*)(krow + c0);
      s16x8 a1 = *(const s16x8*)(krow + (c0 ^ 64));
      s4[c] = (f32x4){0.f, 0.f, 0.f, 0.f};
      s4[c] = MFMA16(a0, aq[0], s4[c]);
      s4[c] = MFMA16(a1, aq[1], s4[c]);
    }

    // rel: G^T = mfma(E, Q), 2-slot rotating chain; skew-gather via per-wave LDS
    if (has_rel) {
#pragma unroll
      for (int c2 = 0; c2 < 5; c2++) {
        s16x8 cur0 = (c2 & 1) ? eb0 : ea0;
        s16x8 cur1 = (c2 & 1) ? eb1 : ea1;
        if (c2 + 2 < 5) {
          const u16* epn = ep0 + (size_t)(c2 + 2) * 16 * 64;
          if (c2 & 1) { eb0 = *(const s16x8*)(epn); eb1 = *(const s16x8*)(epn + 32); }
          else        { ea0 = *(const s16x8*)(epn); ea1 = *(const s16x8*)(epn + 32); }
        }
        f32x4 g = (f32x4){0.f, 0.f, 0.f, 0.f};
        g = MFMA16(cur0, aq[0], g);
        g = MFMA16(cur1, aq[1], g);
        *(f32x4*)(gw + 84 * lo + c2 * 16 + 4 * hi) = g;
      }
      const int dd = lw - j0;
      if (dd >= 64) {
#pragma unroll
        for (int c = 0; c < 4; c++)
#pragma unroll
          for (int reg = 0; reg < 4; reg++)
            s4[c][reg] += gw[83 * lo + 15 + c * 16 + 4 * hi + reg];
      } else {
        const int rmax = dd + lo;
#pragma unroll
        for (int c = 0; c < 4; c++)
#pragma unroll
          for (int reg = 0; reg < 4; reg++) {
            int jr = c * 16 + 4 * hi + reg;
            float g = gw[83 * lo + 15 + jr];
            s4[c][reg] += (jr <= rmax) ? g : 0.f;
          }
      }
    }

    // V frags: 2x b128 per f (quad-permuted storage), K-style addressing
    s16x8 v0f[4], v1f[4];
#pragma unroll
    for (int f = 0; f < 4; f++) {
      const char* vrow = (const char*)&Vts[buf][0] + (f * 16 + lo) * 128;
      v0f[f] = *(const s16x8*)(vrow + c0);
      v1f[f] = *(const s16x8*)(vrow + (c0 ^ 64));
    }

    // in-lane softmax (base-2) with defer-max (THR=8)
    float mta = fmaxf(fmaxf(fmaxf(s4[0][0], s4[0][1]), fmaxf(s4[0][2], s4[0][3])),
                      fmaxf(fmaxf(s4[1][0], s4[1][1]), fmaxf(s4[1][2], s4[1][3])));
    float mtb = fmaxf(fmaxf(fmaxf(s4[2][0], s4[2][1]), fmaxf(s4[2][2], s4[2][3])),
                      fmaxf(fmaxf(s4[3][0], s4[3][1]), fmaxf(s4[3][2], s4[3][3])));
    float mt = fmaxf(mta, mtb);
    mt = fmaxf(mt, __shfl_xor(mt, 16, 64));
    mt = fmaxf(mt, __shfl_xor(mt, 32, 64));
    if (!__all(mt - m_run <= 8.f)) {
      float mnew = fmaxf(m_run, mt);
      float scl = exp2f(m_run - mnew);
      m_run = mnew;
      l_run *= scl;
#pragma unroll
      for (int f = 0; f < 4; f++)
#pragma unroll
        for (int reg = 0; reg < 4; reg++) oacc[f][reg] *= scl;
    }

    unsigned w8[8];
#pragma unroll
    for (int c = 0; c < 4; c++) {
      float a0 = exp2f(s4[c][0] - m_run), a1 = exp2f(s4[c][1] - m_run);
      float a2 = exp2f(s4[c][2] - m_run), a3 = exp2f(s4[c][3] - m_run);
      asm("v_cvt_pk_bf16_f32 %0, %1, %2" : "=v"(w8[c * 2]) : "v"(a0), "v"(a1));
      asm("v_cvt_pk_bf16_f32 %0, %1, %2" : "=v"(w8[c * 2 + 1]) : "v"(a2), "v"(a3));
    }

    union UU { uint4 u; s16x8 v; };
    UU pb0, pb1;
    pb0.u = make_uint4(w8[0], w8[1], w8[2], w8[3]);
    pb1.u = make_uint4(w8[4], w8[5], w8[6], w8[7]);

    __builtin_amdgcn_s_setprio(1);
    // l-sum on the matrix pipe: psum = ones . P
    f32x4 ps = (f32x4){0.f, 0.f, 0.f, 0.f};
    ps = MFMA16(ones8, pb0.v, ps);
    ps = MFMA16(ones8, pb1.v, ps);

    // O^T += V^T . P
#pragma unroll
    for (int f = 0; f < 4; f++) {
      oacc[f] = MFMA16(v0f[f], pb0.v, oacc[f]);
      oacc[f] = MFMA16(v1f[f], pb1.v, oacc[f]);
    }
    __builtin_amdgcn_s_setprio(0);

    l_run += ps[0];
    buf ^= 1;
  }

  const float inv = 1.f / l_run;
  const size_t orow = (size_t)(bb * LSEQ + lw + lo) * 1024 + hh * 64;
#pragma unroll
  for (int f = 0; f < 4; f++) {
    ushort4 o;
    o.x = f2b(oacc[f][0] * inv); o.y = f2b(oacc[f][1] * inv);
    o.z = f2b(oacc[f][2] * inv); o.w = f2b(oacc[f][3] * inv);
    *(ushort4*)(Ob + orow + f * 16 + 4 * hi) = o;
  }
}

// ------------- LayerNorm: 1 wave per row (16 f32/lane), 4 rows/block, no barriers -------------
__global__ __launch_bounds__(256) void k_layernorm(const float* __restrict__ X, const float* __restrict__ gwt,
                                                   const float* __restrict__ bwt, float* __restrict__ outF,
                                                   u16* __restrict__ outB) {
  const int lane = threadIdx.x & 63, wave = threadIdx.x >> 6;
  const int row = blockIdx.x * 4 + wave;
  const float* xr = X + (size_t)row * 1024 + lane * 16;
  float4 v[4];
  float s = 0.f, s2 = 0.f;
#pragma unroll
  for (int i = 0; i < 4; i++) {
    v[i] = *(const float4*)(xr + i * 4);
    s += (v[i].x + v[i].y) + (v[i].z + v[i].w);
    s2 += (v[i].x * v[i].x + v[i].y * v[i].y) + (v[i].z * v[i].z + v[i].w * v[i].w);
  }
#pragma unroll
  for (int msk = 1; msk <= 32; msk <<= 1) {
    s += __shfl_xor(s, msk, 64);
    s2 += __shfl_xor(s2, msk, 64);
  }
  const float mean = s * (1.f / 1024.f);
  const float var = s2 * (1.f / 1024.f) - mean * mean;
  const float rs = rsqrtf(var + 1e-6f);
#pragma unroll
  for (int i = 0; i < 4; i++) {
    float4 g4 = *(const float4*)(gwt + lane * 16 + i * 4);
    float4 b4 = *(const float4*)(bwt + lane * 16 + i * 4);
    float4 o;
    o.x = (v[i].x - mean) * rs * g4.x + b4.x;
    o.y = (v[i].y - mean) * rs * g4.y + b4.y;
    o.z = (v[i].z - mean) * rs * g4.z + b4.z;
    o.w = (v[i].w - mean) * rs * g4.w + b4.w;
    if (outF) *(float4*)(outF + (size_t)row * 1024 + lane * 16 + i * 4) = o;
    if (outB) {
      ushort4 ob;
      ob.x = f2b(o.x); ob.y = f2b(o.y); ob.z = f2b(o.z); ob.w = f2b(o.w);
      *(ushort4*)(outB + (size_t)row * 1024 + lane * 16 + i * 4) = ob;
    }
  }
}

extern "C" void kernel_launch(void* const* d_in, const int* in_sizes, int n_in,
                              void* d_out, int out_size, void* d_ws, size_t ws_size,
                              hipStream_t stream) {
  const float* x   = (const float*)d_in[0];
  const float* Wq  = (const float*)d_in[1];
  const float* bq  = (const float*)d_in[2];
  const float* Wk  = (const float*)d_in[3];
  const float* bk  = (const float*)d_in[4];
  const float* Wv  = (const float*)d_in[5];
  const float* bv  = (const float*)d_in[6];
  const float* Wo  = (const float*)d_in[7];
  const float* bo  = (const float*)d_in[8];
  const float* E   = (const float*)d_in[9];
  const float* W1  = (const float*)d_in[10];
  const float* b1  = (const float*)d_in[11];
  const float* W2  = (const float*)d_in[12];
  const float* b2  = (const float*)d_in[13];
  const float* g1  = (const float*)d_in[14];
  const float* be1 = (const float*)d_in[15];
  const float* g2  = (const float*)d_in[16];
  const float* be2 = (const float*)d_in[17];

  char* ws = (char*)d_ws;
  const size_t MB = 1ull << 20;
  u16* Wqt = (u16*)(ws + 0 * MB);          // 6MB contiguous [3072][1024]
  u16* Wot = (u16*)(ws + 6 * MB);          // 2MB
  u16* W1t = (u16*)(ws + 8 * MB);          // 8MB [4096][1024]
  u16* W2t = (u16*)(ws + 16 * MB);         // 8MB [1024][4096]
  u16* Ebf = (u16*)(ws + 24 * MB);         // 256KB (+ slack for OOB band reads)
  float* bcat = (float*)(ws + 24 * MB + 512 * 1024);  // 12KB
  u16* xb  = (u16*)(ws + 25 * MB);         // 8MB [4096][1024]
  u16* qb  = (u16*)(ws + 33 * MB);         // 8MB head-major (QSCALE'd)
  u16* kb  = (u16*)(ws + 41 * MB);         // 8MB head-major
  u16* vt  = (u16*)(ws + 49 * MB);         // 8MB [bh][64][L] quad-permuted
  u16* ao  = (u16*)(ws + 57 * MB);         // 8MB [4096][1024]
  float* t1 = (float*)(ws + 65 * MB);      // 16MB f32
  u16* o1b  = (u16*)(ws + 25 * MB);        // reuse xb
  u16* h1b  = (u16*)(ws + 49 * MB);        // reuse vt/ao/t1, 32MB
  float* outF = (float*)d_out;

  // 1) fused prep (1 launch)
  k_prep_all<<<4129, 256, 0, stream>>>(x, E, bq, bk, bv, Wq, Wk, Wv, Wo, W1, W2,
                                       xb, Ebf, bcat, Wqt, Wot, W1t, W2t);

  // 2) fused QKV projection, 256x128 tile / 8 waves (writes qb, kb, vt)
  k_gemm<256, 128, 4, 32><<<dim3(24, 16), 512, 0, stream>>>(xb, Wqt, bcat, nullptr, qb, 4096, 3072, 1024);

  // 3) rel-pos flash attention -> ao
  k_attn<<<dim3(512), 512, 0, stream>>>(qb, kb, vt, Ebf, ao);

  // 4) O-proj + residual(x, f32) -> t1, BK=64
  k_gemm<128, 64, 8, 64><<<dim3(16, 32), 256, 0, stream>>>(ao, Wot, bo, x, t1, 4096, 1024, 1024);

  // 5) LN1 -> o1b (bf16 only), wave-per-row
  k_layernorm<<<1024, 256, 0, stream>>>(t1, g1, be1, nullptr, o1b);

  // 6) FFN1: relu(o1 @ W1 + b1), 256x128 tile / 8 waves -> h1b bf16
  k_gemm<256, 128, 3, 32><<<dim3(32, 16), 512, 0, stream>>>(o1b, W1t, b1, nullptr, h1b, 4096, 4096, 1024);

  // 7) FFN2 + residual(o1b, bf16) -> d_out f32, BK=64
  k_gemm<128, 64, 16, 64><<<dim3(16, 32), 256, 0, stream>>>(h1b, W2t, b2, o1b, outF, 4096, 1024, 4096);

  // 8) LN2 in-place on d_out, wave-per-row
  k_layernorm<<<1024, 256, 0, stream>>>(outF, g2, be2, outF, nullptr);
}

// Round 17
// 304.330 us; speedup vs baseline: 1.0032x; 1.0032x over previous
//
#include <hip/hip_runtime.h>

typedef unsigned short u16;
typedef __attribute__((ext_vector_type(8))) short s16x8;
typedef __attribute__((ext_vector_type(4))) float f32x4;

#define MFMA16(a,b,c) __builtin_amdgcn_mfma_f32_16x16x32_bf16((a),(b),(c),0,0,0)
#define LSEQ 2048
#define QSCALE 0.18033688011112042f  /* 0.125 * log2(e) */

__device__ __forceinline__ u16 f2b(float f) {
  union { float f; unsigned u; } v; v.f = f;
  unsigned r = v.u + 0x7FFFu + ((v.u >> 16) & 1u);
  return (u16)(r >> 16);
}
__device__ __forceinline__ void g2l16(const void* g, void* l) {
  __builtin_amdgcn_global_load_lds(
      (const __attribute__((address_space(1))) unsigned int*)g,
      (__attribute__((address_space(3))) unsigned int*)l, 16, 0, 0);
}

// ------------- fused prep: cvt(x), cvt(E), bias concat, 6 weight transposes -------------
__global__ __launch_bounds__(256) void k_prep_all(
    const float* __restrict__ x, const float* __restrict__ E,
    const float* __restrict__ bq, const float* __restrict__ bk, const float* __restrict__ bv,
    const float* __restrict__ Wq, const float* __restrict__ Wk, const float* __restrict__ Wv,
    const float* __restrict__ Wo, const float* __restrict__ W1, const float* __restrict__ W2,
    u16* __restrict__ xb, u16* __restrict__ Ebf, float* __restrict__ bcat,
    u16* __restrict__ Wqt, u16* __restrict__ Wot, u16* __restrict__ W1t, u16* __restrict__ W2t) {
  __shared__ float T[64][65];
  const int b = blockIdx.x, tid = threadIdx.x;

  if (b < 1056) {
    const float* src = (b < 1024) ? x : E;
    u16* dst = (b < 1024) ? xb : Ebf;
    const int base = (b < 1024) ? b * 4096 : (b - 1024) * 4096;
#pragma unroll
    for (int p = 0; p < 4; p++) {
      int i = base + p * 1024 + tid * 4;
      float4 v = *(const float4*)(src + i);
      ushort4 o;
      o.x = f2b(v.x); o.y = f2b(v.y); o.z = f2b(v.z); o.w = f2b(v.w);
      *(ushort4*)(dst + i) = o;
    }
    return;
  }
  if (b == 1056) {
    for (int i = tid; i < 3072; i += 256)
      bcat[i] = (i < 1024) ? bq[i] : (i < 2048) ? bk[i - 1024] : bv[i - 2048];
    return;
  }

  const int idx = b - 1057;
  const float* W; u16* Wt; int K, N, bx, by;
  if (idx < 1024) {
    const int m = idx >> 8, ti = idx & 255;
    const float* ws4[4] = {Wq, Wk, Wv, Wo};
    W = ws4[m];
    Wt = (m < 3) ? (Wqt + (size_t)m * 1048576) : Wot;
    K = 1024; N = 1024; bx = ti & 15; by = ti >> 4;
  } else if (idx < 2048) {
    const int ti = idx - 1024;
    W = W1; Wt = W1t; K = 1024; N = 4096; bx = ti & 63; by = ti >> 6;
  } else {
    const int ti = idx - 2048;
    W = W2; Wt = W2t; K = 4096; N = 1024; bx = ti & 15; by = ti >> 4;
  }
  const int k0 = by * 64, n0 = bx * 64;
  const int r = tid >> 4, c4 = (tid & 15) * 4;
#pragma unroll
  for (int i = 0; i < 4; i++) {
    float4 v = *(const float4*)(W + (size_t)(k0 + r + i * 16) * N + n0 + c4);
    T[r + i * 16][c4 + 0] = v.x; T[r + i * 16][c4 + 1] = v.y;
    T[r + i * 16][c4 + 2] = v.z; T[r + i * 16][c4 + 3] = v.w;
  }
  __syncthreads();
#pragma unroll
  for (int i = 0; i < 4; i++) {
    int nl = r + i * 16;
    ushort4 o;
    o.x = f2b(T[c4 + 0][nl]); o.y = f2b(T[c4 + 1][nl]);
    o.z = f2b(T[c4 + 2][nl]); o.w = f2b(T[c4 + 3][nl]);
    *(ushort4*)(Wt + (size_t)(n0 + nl) * K + k0 + c4) = o;
  }
}

// ------------- bf16 MFMA GEMM, gload_lds dbuf, swizzled LDS, BK=32/64 -------------
// BM=128: 4 waves.  BM=256 (BN=128): 8 waves, 64x64/wave.
// FLAGS: 1=RELU, 2=BF16OUT, 4=QKV, 8=RESID_F32, 16=RESID_BF16
template <int BM, int BN, int FLAGS, int BK>
__global__ __launch_bounds__(BM == 256 ? 512 : 256, BM == 256 ? 4 : 2)
void k_gemm(const u16* __restrict__ A, const u16* __restrict__ Bt,
            const float* __restrict__ bias, const void* __restrict__ resid,
            void* __restrict__ Cout, int M, int N, int K) {
  constexpr int MI = (BN == 128) ? 4 : 2;
  constexpr int KH = BK / 32;
  __shared__ __align__(16) u16 As[2][KH][BM * 32];
  __shared__ __align__(16) u16 Bs[2][KH][BN * 32];
  const int tid = threadIdx.x;
  const int lane = tid & 63, wave = tid >> 6;
  const int lo = lane & 15, hi = lane >> 4;
  const int WROW = (BN == 128) ? (wave >> 1) * 64 : wave * 32;
  const int WCOL = (BN == 128) ? (wave & 1) * 64 : 0;
  const int m0 = blockIdx.y * BM, n0 = blockIdx.x * BN;

  const int colg = ((lane & 3) * 16) ^ (((lane >> 3) & 3) << 4);
  const int arow = wave * 32 + (lane >> 2);
  const int swzr = ((lane >> 1) & 3) << 4;

  f32x4 acc[MI][4];
#pragma unroll
  for (int mi = 0; mi < MI; mi++)
#pragma unroll
    for (int ni = 0; ni < 4; ni++) acc[mi][ni] = (f32x4){0.f, 0.f, 0.f, 0.f};

  const char* Ab = (const char*)A;
  const char* Bb = (const char*)Bt;
  const int nt = K / BK;

  auto stage = [&](int buf, int t) {
#pragma unroll
    for (int h = 0; h < KH; h++) {
      const int k0 = t * BK + h * 32;
      char* ad = (char*)&As[buf][h][0] + wave * 2048;
      const char* as = Ab + ((size_t)(m0 + arow) * K + k0) * 2 + colg;
      g2l16(as, ad);
      g2l16(as + (size_t)16 * K * 2, ad + 1024);
      if (BM == 256) {
        char* bd = (char*)&Bs[buf][h][0] + wave * 1024;
        const char* bs = Bb + ((size_t)(n0 + wave * 16 + (lane >> 2)) * K + k0) * 2 + colg;
        g2l16(bs, bd);
      } else if (BN == 128) {
        char* bd = (char*)&Bs[buf][h][0] + wave * 2048;
        const char* bs = Bb + ((size_t)(n0 + arow) * K + k0) * 2 + colg;
        g2l16(bs, bd);
        g2l16(bs + (size_t)16 * K * 2, bd + 1024);
      } else {
        char* bd = (char*)&Bs[buf][h][0] + wave * 1024;
        const int brow = wave * 16 + (lane >> 2);
        const char* bs = Bb + ((size_t)(n0 + brow) * K + k0) * 2 + colg;
        g2l16(bs, bd);
      }
    }
  };

  stage(0, 0);
  int buf = 0;
  for (int t = 0; t < nt; t++) {
    __syncthreads();
    if (t + 1 < nt) stage(buf ^ 1, t + 1);
#pragma unroll
    for (int h = 0; h < KH; h++) {
      const char* ab = (const char*)&As[buf][h][0];
      const char* bb2 = (const char*)&Bs[buf][h][0];
      s16x8 af[MI], bfr[4];
#pragma unroll
      for (int mi = 0; mi < MI; mi++) {
        int row = WROW + mi * 16 + lo;
        af[mi] = *(const s16x8*)(ab + row * 64 + ((hi * 16) ^ swzr));
      }
#pragma unroll
      for (int ni = 0; ni < 4; ni++) {
        int row = WCOL + ni * 16 + lo;
        bfr[ni] = *(const s16x8*)(bb2 + row * 64 + ((hi * 16) ^ swzr));
      }
#pragma unroll
      for (int mi = 0; mi < MI; mi++)
#pragma unroll
        for (int ni = 0; ni < 4; ni++)
          acc[mi][ni] = MFMA16(af[mi], bfr[ni], acc[mi][ni]);
    }
    buf ^= 1;
  }

#pragma unroll
  for (int mi = 0; mi < MI; mi++)
#pragma unroll
    for (int ni = 0; ni < 4; ni++) {
      const int mb = m0 + WROW + mi * 16 + hi * 4;
      const int n = n0 + WCOL + ni * 16 + lo;
      float v4[4];
#pragma unroll
      for (int reg = 0; reg < 4; reg++) {
        float v = acc[mi][ni][reg] + bias[n];
        if (FLAGS & 8) v += ((const float*)resid)[(size_t)(mb + reg) * N + n];
        if (FLAGS & 16) {
          union { unsigned u; float f; } q;
          q.u = ((unsigned)((const u16*)resid)[(size_t)(mb + reg) * N + n]) << 16;
          v += q.f;
        }
        if (FLAGS & 1) v = fmaxf(v, 0.f);
        v4[reg] = v;
      }
      if (FLAGS & 4) {
        const int seg = n >> 10, nn = n & 1023;
        const int hh = nn >> 6, dd = nn & 63;
        const int bb = mb >> 11, ll = mb & 2047;
        u16* dst = (u16*)Cout + (size_t)seg * 4194304;
        if (seg == 0) {
#pragma unroll
          for (int reg = 0; reg < 4; reg++)
            dst[((size_t)(bb * 16 + hh) * LSEQ + ll + reg) * 64 + dd] = f2b(v4[reg] * QSCALE);
        } else if (seg == 1) {
#pragma unroll
          for (int reg = 0; reg < 4; reg++)
            dst[((size_t)(bb * 16 + hh) * LSEQ + ll + reg) * 64 + dd] = f2b(v4[reg]);
        } else {
          // V^T, quad-permuted within each 32-seq group so k_attn reads b128 frags:
          // j-quad lq -> position quad (lq<4 ? 2lq : 2(lq-4)+1)
          const int lq = (ll >> 2) & 7;
          const int pq = (lq < 4) ? (lq * 2) : ((lq - 4) * 2 + 1);
          const int llp = (ll & ~31) | (pq << 2);
          ushort4 o;
          o.x = f2b(v4[0]); o.y = f2b(v4[1]); o.z = f2b(v4[2]); o.w = f2b(v4[3]);
          *(ushort4*)&((u16*)dst)[((size_t)(bb * 16 + hh) * 64 + dd) * LSEQ + llp] = o;
        }
      } else if (FLAGS & 2) {
        u16* dst = (u16*)Cout;
#pragma unroll
        for (int reg = 0; reg < 4; reg++) dst[(size_t)(mb + reg) * N + n] = f2b(v4[reg]);
      } else {
        float* dst = (float*)Cout;
#pragma unroll
        for (int reg = 0; reg < 4; reg++) dst[(size_t)(mb + reg) * N + n] = v4[reg];
      }
    }
}

// ------------- fused rel-pos flash attention: transposed dataflow, 8 waves/block -------------
// V stored quad-permuted -> V frags are 2x ds_read_b128 with K-style addressing.
// First two E-load pairs issued before the QK MFMA cluster (latency hidden under it).
__global__ __launch_bounds__(512, 4) void k_attn(const u16* __restrict__ Qh, const u16* __restrict__ Kh,
                                                 const u16* __restrict__ Vt, const u16* __restrict__ Eb,
                                                 u16* __restrict__ Ob) {
  __shared__ __align__(16) u16 Ksh[2][64 * 64];
  __shared__ __align__(16) u16 Vts[2][64 * 64];
  __shared__ __align__(16) float Gsh[8][16 * 84];

  const int tid = threadIdx.x;
  const int lane = tid & 63, wave = tid >> 6;
  const int lo = lane & 15, hi = lane >> 4;

  const int hb = blockIdx.x;
  const int x = hb & 7;
  const int kk = hb >> 3;
  const int bh = x * 4 + (kk >> 4);
  const int ti = (kk & 32) ? (15 - (kk & 15)) : (kk & 15);
  const int l0 = ti * 128;
  const int bb = bh >> 4, hh = bh & 15;
  const int lw = l0 + wave * 16;

  const u16* Qb = Qh + (size_t)bh * LSEQ * 64;
  const char* Kb = (const char*)(Kh + (size_t)bh * LSEQ * 64);
  const char* Vb = (const char*)(Vt + (size_t)bh * 64 * LSEQ);

  const int colsw = ((lane & 7) * 16) ^ (((lane >> 3) & 7) << 4);
  const int swzv = (lo & 7) << 4;
  const int c0 = (hi * 16) ^ swzv;

  auto stageKV = [&](int buf_, int j0_) {
    char* kd = (char*)&Ksh[buf_][0] + wave * 1024;
    const char* ks = Kb + (size_t)(j0_ + wave * 8 + (lane >> 3)) * 128 + colsw;
    g2l16(ks, kd);
    char* vd = (char*)&Vts[buf_][0] + wave * 1024;
    const char* vs = Vb + (size_t)(wave * 8 + (lane >> 3)) * (LSEQ * 2) + (size_t)j0_ * 2 + colsw;
    g2l16(vs, vd);
  };

  s16x8 aq[2];
  aq[0] = *(const s16x8*)(Qb + (size_t)(lw + lo) * 64 + hi * 8);
  aq[1] = *(const s16x8*)(Qb + (size_t)(lw + lo) * 64 + 32 + hi * 8);

  const s16x8 ones8 = {16256, 16256, 16256, 16256, 16256, 16256, 16256, 16256};  // bf16 1.0

  float m_run = -1e30f, l_run = 0.f;
  f32x4 oacc[4];
#pragma unroll
  for (int f = 0; f < 4; f++) oacc[f] = (f32x4){0.f, 0.f, 0.f, 0.f};

  float* gw = &Gsh[wave][0];

  stageKV(0, 0);
  int buf = 0;

  for (int t = 0; t < 32; t++) {
    const int j0 = t * 64;
    const bool has_rel = (j0 <= lw);
    __syncthreads();
    if (t < 31) stageKV(buf ^ 1, j0 + 64);

    // E pairs 0 and 1 issued EARLY (hidden under the QK cluster); slots rotate a/b.
    s16x8 ea0, ea1, eb0, eb1;
    const u16* ep0 = Eb;
    if (has_rel) {
      const int waveBase = 2032 - lw + j0;
      ep0 = Eb + (size_t)(waveBase + lo) * 64 + hi * 8;
      ea0 = *(const s16x8*)(ep0);
      ea1 = *(const s16x8*)(ep0 + 32);
      eb0 = *(const s16x8*)(ep0 + 16 * 64);
      eb1 = *(const s16x8*)(ep0 + 16 * 64 + 32);
    }

    // S^T = mfma(K, Q)
    f32x4 s4[4];
#pragma unroll
    for (int c = 0; c < 4; c++) {
      const char* krow = (const char*)&Ksh[buf][0] + (c * 16 + lo) * 128;
      s16x8 a0 = *(const s16x8*)(krow + c0);
      s16x8 a1 = *(const s16x8*)(krow + (c0 ^ 64));
      s4[c] = (f32x4){0.f, 0.f, 0.f, 0.f};
      s4[c] = MFMA16(a0, aq[0], s4[c]);
      s4[c] = MFMA16(a1, aq[1], s4[c]);
    }

    // rel: G^T = mfma(E, Q), 2-slot rotating chain; skew-gather via per-wave LDS
    if (has_rel) {
#pragma unroll
      for (int c2 = 0; c2 < 5; c2++) {
        s16x8 cur0 = (c2 & 1) ? eb0 : ea0;
        s16x8 cur1 = (c2 & 1) ? eb1 : ea1;
        if (c2 + 2 < 5) {
          const u16* epn = ep0 + (size_t)(c2 + 2) * 16 * 64;
          if (c2 & 1) { eb0 = *(const s16x8*)(epn); eb1 = *(const s16x8*)(epn + 32); }
          else        { ea0 = *(const s16x8*)(epn); ea1 = *(const s16x8*)(epn + 32); }
        }
        f32x4 g = (f32x4){0.f, 0.f, 0.f, 0.f};
        g = MFMA16(cur0, aq[0], g);
        g = MFMA16(cur1, aq[1], g);
        *(f32x4*)(gw + 84 * lo + c2 * 16 + 4 * hi) = g;
      }
      const int dd = lw - j0;
      if (dd >= 64) {
#pragma unroll
        for (int c = 0; c < 4; c++)
#pragma unroll
          for (int reg = 0; reg < 4; reg++)
            s4[c][reg] += gw[83 * lo + 15 + c * 16 + 4 * hi + reg];
      } else {
        const int rmax = dd + lo;
#pragma unroll
        for (int c = 0; c < 4; c++)
#pragma unroll
          for (int reg = 0; reg < 4; reg++) {
            int jr = c * 16 + 4 * hi + reg;
            float g = gw[83 * lo + 15 + jr];
            s4[c][reg] += (jr <= rmax) ? g : 0.f;
          }
      }
    }

    // V frags: 2x b128 per f (quad-permuted storage), K-style addressing
    s16x8 v0f[4], v1f[4];
#pragma unroll
    for (int f = 0; f < 4; f++) {
      const char* vrow = (const char*)&Vts[buf][0] + (f * 16 + lo) * 128;
      v0f[f] = *(const s16x8*)(vrow + c0);
      v1f[f] = *(const s16x8*)(vrow + (c0 ^ 64));
    }

    // in-lane softmax (base-2) with defer-max (THR=8)
    float mta = fmaxf(fmaxf(fmaxf(s4[0][0], s4[0][1]), fmaxf(s4[0][2], s4[0][3])),
                      fmaxf(fmaxf(s4[1][0], s4[1][1]), fmaxf(s4[1][2], s4[1][3])));
    float mtb = fmaxf(fmaxf(fmaxf(s4[2][0], s4[2][1]), fmaxf(s4[2][2], s4[2][3])),
                      fmaxf(fmaxf(s4[3][0], s4[3][1]), fmaxf(s4[3][2], s4[3][3])));
    float mt = fmaxf(mta, mtb);
    mt = fmaxf(mt, __shfl_xor(mt, 16, 64));
    mt = fmaxf(mt, __shfl_xor(mt, 32, 64));
    if (!__all(mt - m_run <= 8.f)) {
      float mnew = fmaxf(m_run, mt);
      float scl = exp2f(m_run - mnew);
      m_run = mnew;
      l_run *= scl;
#pragma unroll
      for (int f = 0; f < 4; f++)
#pragma unroll
        for (int reg = 0; reg < 4; reg++) oacc[f][reg] *= scl;
    }

    unsigned w8[8];
#pragma unroll
    for (int c = 0; c < 4; c++) {
      float a0 = exp2f(s4[c][0] - m_run), a1 = exp2f(s4[c][1] - m_run);
      float a2 = exp2f(s4[c][2] - m_run), a3 = exp2f(s4[c][3] - m_run);
      asm("v_cvt_pk_bf16_f32 %0, %1, %2" : "=v"(w8[c * 2]) : "v"(a0), "v"(a1));
      asm("v_cvt_pk_bf16_f32 %0, %1, %2" : "=v"(w8[c * 2 + 1]) : "v"(a2), "v"(a3));
    }

    union UU { uint4 u; s16x8 v; };
    UU pb0, pb1;
    pb0.u = make_uint4(w8[0], w8[1], w8[2], w8[3]);
    pb1.u = make_uint4(w8[4], w8[5], w8[6], w8[7]);

    __builtin_amdgcn_s_setprio(1);
    // l-sum on the matrix pipe: psum = ones . P
    f32x4 ps = (f32x4){0.f, 0.f, 0.f, 0.f};
    ps = MFMA16(ones8, pb0.v, ps);
    ps = MFMA16(ones8, pb1.v, ps);

    // O^T += V^T . P
#pragma unroll
    for (int f = 0; f < 4; f++) {
      oacc[f] = MFMA16(v0f[f], pb0.v, oacc[f]);
      oacc[f] = MFMA16(v1f[f], pb1.v, oacc[f]);
    }
    __builtin_amdgcn_s_setprio(0);

    l_run += ps[0];
    buf ^= 1;
  }

  const float inv = 1.f / l_run;
  const size_t orow = (size_t)(bb * LSEQ + lw + lo) * 1024 + hh * 64;
#pragma unroll
  for (int f = 0; f < 4; f++) {
    ushort4 o;
    o.x = f2b(oacc[f][0] * inv); o.y = f2b(oacc[f][1] * inv);
    o.z = f2b(oacc[f][2] * inv); o.w = f2b(oacc[f][3] * inv);
    *(ushort4*)(Ob + orow + f * 16 + 4 * hi) = o;
  }
}

// ------------- LayerNorm: 1 wave per row (16 f32/lane), 4 rows/block, no barriers -------------
__global__ __launch_bounds__(256) void k_layernorm(const float* __restrict__ X, const float* __restrict__ gwt,
                                                   const float* __restrict__ bwt, float* __restrict__ outF,
                                                   u16* __restrict__ outB) {
  const int lane = threadIdx.x & 63, wave = threadIdx.x >> 6;
  const int row = blockIdx.x * 4 + wave;
  const float* xr = X + (size_t)row * 1024 + lane * 16;
  float4 v[4];
  float s = 0.f, s2 = 0.f;
#pragma unroll
  for (int i = 0; i < 4; i++) {
    v[i] = *(const float4*)(xr + i * 4);
    s += (v[i].x + v[i].y) + (v[i].z + v[i].w);
    s2 += (v[i].x * v[i].x + v[i].y * v[i].y) + (v[i].z * v[i].z + v[i].w * v[i].w);
  }
#pragma unroll
  for (int msk = 1; msk <= 32; msk <<= 1) {
    s += __shfl_xor(s, msk, 64);
    s2 += __shfl_xor(s2, msk, 64);
  }
  const float mean = s * (1.f / 1024.f);
  const float var = s2 * (1.f / 1024.f) - mean * mean;
  const float rs = rsqrtf(var + 1e-6f);
#pragma unroll
  for (int i = 0; i < 4; i++) {
    float4 g4 = *(const float4*)(gwt + lane * 16 + i * 4);
    float4 b4 = *(const float4*)(bwt + lane * 16 + i * 4);
    float4 o;
    o.x = (v[i].x - mean) * rs * g4.x + b4.x;
    o.y = (v[i].y - mean) * rs * g4.y + b4.y;
    o.z = (v[i].z - mean) * rs * g4.z + b4.z;
    o.w = (v[i].w - mean) * rs * g4.w + b4.w;
    if (outF) *(float4*)(outF + (size_t)row * 1024 + lane * 16 + i * 4) = o;
    if (outB) {
      ushort4 ob;
      ob.x = f2b(o.x); ob.y = f2b(o.y); ob.z = f2b(o.z); ob.w = f2b(o.w);
      *(ushort4*)(outB + (size_t)row * 1024 + lane * 16 + i * 4) = ob;
    }
  }
}

extern "C" void kernel_launch(void* const* d_in, const int* in_sizes, int n_in,
                              void* d_out, int out_size, void* d_ws, size_t ws_size,
                              hipStream_t stream) {
  const float* x   = (const float*)d_in[0];
  const float* Wq  = (const float*)d_in[1];
  const float* bq  = (const float*)d_in[2];
  const float* Wk  = (const float*)d_in[3];
  const float* bk  = (const float*)d_in[4];
  const float* Wv  = (const float*)d_in[5];
  const float* bv  = (const float*)d_in[6];
  const float* Wo  = (const float*)d_in[7];
  const float* bo  = (const float*)d_in[8];
  const float* E   = (const float*)d_in[9];
  const float* W1  = (const float*)d_in[10];
  const float* b1  = (const float*)d_in[11];
  const float* W2  = (const float*)d_in[12];
  const float* b2  = (const float*)d_in[13];
  const float* g1  = (const float*)d_in[14];
  const float* be1 = (const float*)d_in[15];
  const float* g2  = (const float*)d_in[16];
  const float* be2 = (const float*)d_in[17];

  char* ws = (char*)d_ws;
  const size_t MB = 1ull << 20;
  u16* Wqt = (u16*)(ws + 0 * MB);          // 6MB contiguous [3072][1024]
  u16* Wot = (u16*)(ws + 6 * MB);          // 2MB
  u16* W1t = (u16*)(ws + 8 * MB);          // 8MB [4096][1024]
  u16* W2t = (u16*)(ws + 16 * MB);         // 8MB [1024][4096]
  u16* Ebf = (u16*)(ws + 24 * MB);         // 256KB (+ slack for OOB band reads)
  float* bcat = (float*)(ws + 24 * MB + 512 * 1024);  // 12KB
  u16* xb  = (u16*)(ws + 25 * MB);         // 8MB [4096][1024]
  u16* qb  = (u16*)(ws + 33 * MB);         // 8MB head-major (QSCALE'd)
  u16* kb  = (u16*)(ws + 41 * MB);         // 8MB head-major
  u16* vt  = (u16*)(ws + 49 * MB);         // 8MB [bh][64][L] quad-permuted
  u16* ao  = (u16*)(ws + 57 * MB);         // 8MB [4096][1024]
  float* t1 = (float*)(ws + 65 * MB);      // 16MB f32
  u16* o1b  = (u16*)(ws + 25 * MB);        // reuse xb
  u16* h1b  = (u16*)(ws + 49 * MB);        // reuse vt/ao/t1, 32MB
  float* outF = (float*)d_out;

  // 1) fused prep (1 launch)
  k_prep_all<<<4129, 256, 0, stream>>>(x, E, bq, bk, bv, Wq, Wk, Wv, Wo, W1, W2,
                                       xb, Ebf, bcat, Wqt, Wot, W1t, W2t);

  // 2) fused QKV projection, 256x128 tile / 8 waves (writes qb, kb, vt)
  k_gemm<256, 128, 4, 32><<<dim3(24, 16), 512, 0, stream>>>(xb, Wqt, bcat, nullptr, qb, 4096, 3072, 1024);

  // 3) rel-pos flash attention -> ao
  k_attn<<<dim3(512), 512, 0, stream>>>(qb, kb, vt, Ebf, ao);

  // 4) O-proj + residual(x, f32) -> t1, BK=64
  k_gemm<128, 64, 8, 64><<<dim3(16, 32), 256, 0, stream>>>(ao, Wot, bo, x, t1, 4096, 1024, 1024);

  // 5) LN1 -> o1b (bf16 only), wave-per-row
  k_layernorm<<<1024, 256, 0, stream>>>(t1, g1, be1, nullptr, o1b);

  // 6) FFN1: relu(o1 @ W1 + b1), 256x128 tile / 8 waves -> h1b bf16
  k_gemm<256, 128, 3, 32><<<dim3(32, 16), 512, 0, stream>>>(o1b, W1t, b1, nullptr, h1b, 4096, 4096, 1024);

  // 7) FFN2 + residual(o1b, bf16) -> d_out f32, BK=64
  k_gemm<128, 64, 16, 64><<<dim3(16, 32), 256, 0, stream>>>(h1b, W2t, b2, o1b, outF, 4096, 1024, 4096);

  // 8) LN2 in-place on d_out, wave-per-row
  k_layernorm<<<1024, 256, 0, stream>>>(outF, g2, be2, outF, nullptr);
}